// Round 1
// baseline (143.432 us; speedup 1.0000x reference)
//
#include <hip/hip_runtime.h>

#define DIM 64
#define NB 4096
#define NTOK 32
#define NL 2

typedef __attribute__((ext_vector_type(8))) __bf16 bf16x8;
typedef __attribute__((ext_vector_type(4))) float f32x4;

__device__ __forceinline__ f32x4 mfma16(bf16x8 a, bf16x8 b, f32x4 c) {
  return __builtin_amdgcn_mfma_f32_16x16x32_bf16(a, b, c, 0, 0, 0);
}

// Transpose weights to bf16 [col][k] layout in workspace so B-fragments are
// contiguous 16B loads:  W1t[64][128], G1t[64][128], W2t[64][64], G2t[64][64]
__global__ void prep_w(const float* __restrict__ W1, const float* __restrict__ G1,
                       const float* __restrict__ W2, const float* __restrict__ G2,
                       __bf16* __restrict__ ws) {
  int i = blockIdx.x * 256 + threadIdx.x;
  if (i < 8192) {
    int c = i >> 7, k = i & 127;
    ws[i]        = (__bf16)W1[k * 64 + c];
    ws[8192 + i] = (__bf16)G1[k * 64 + c];
  } else if (i < 12288) {
    int j = i - 8192;
    int c = j >> 6, k = j & 63;
    ws[16384 + j] = (__bf16)W2[k * 64 + c];
    ws[20480 + j] = (__bf16)G2[k * 64 + c];
  }
}

// One wave = one batch element, all 4 (tower,layer) combos + score.
// All LDS regions are wave-private -> no __syncthreads needed anywhere.
__global__ __launch_bounds__(256) void ckan_main(
    const int* __restrict__ items,
    const int* __restrict__ user_h, const int* __restrict__ user_r, const int* __restrict__ user_t,
    const int* __restrict__ item_h, const int* __restrict__ item_r, const int* __restrict__ item_t,
    const float* __restrict__ ent, const float* __restrict__ rel,
    const __bf16* __restrict__ wt, const float* __restrict__ w3,
    float* __restrict__ out)
{
  __shared__ __align__(16) __bf16 s1buf[128][72];   // stride 144B: 16B-aligned rows
  __shared__ __align__(16) __bf16 g1buf[128][72];
  __shared__ float attbuf[128];
  __shared__ int hidx[128], ridx[128], tidx[128];

  const int tid  = threadIdx.x;
  const int w    = tid >> 6;     // wave id 0..3
  const int lane = tid & 63;
  const int b    = blockIdx.x * 4 + w;
  const int r16  = lane & 15;    // row-in-tile (A) / col-in-tile (B, C/D)
  const int g4   = lane >> 4;    // k-group
  const int rb   = w * 32;       // this wave's private LDS row base

  const __bf16* __restrict__ W1t = wt;
  const __bf16* __restrict__ G1t = wt + 8192;
  const __bf16* __restrict__ W2t = wt + 16384;
  const __bf16* __restrict__ G2t = wt + 20480;

  const f32x4 zero4 = {0.f, 0.f, 0.f, 0.f};
  float layer_dot = 0.f;   // per-lane partial of sum_l <u_l, i_l> (4x replicated)

  for (int l = 0; l < NL; ++l) {
    float uvec[4];
#pragma unroll
    for (int tower = 0; tower < 2; ++tower) {
      const int* __restrict__ Hp = tower ? item_h : user_h;
      const int* __restrict__ Rp = tower ? item_r : user_r;
      const int* __restrict__ Tp = tower ? item_t : user_t;
      const int ibase = (l * NB + b) * NTOK;
      if (lane < 32) {
        hidx[rb + lane] = Hp[ibase + lane];
        ridx[rb + lane] = Rp[ibase + lane];
        tidx[rb + lane] = Tp[ibase + lane];
      }

      const int h0 = hidx[rb + r16] * DIM;
      const int h1 = hidx[rb + 16 + r16] * DIM;
      const int rr0 = ridx[rb + r16] * DIM;
      const int rr1 = ridx[rb + 16 + r16] * DIM;

      // ---- GEMM1: x[32,128] @ {W1,G1}[128,64], A gathered from global ----
      f32x4 accS[2][4], accG[2][4];
#pragma unroll
      for (int m = 0; m < 2; ++m)
#pragma unroll
        for (int n = 0; n < 4; ++n) { accS[m][n] = zero4; accG[m][n] = zero4; }

#pragma unroll
      for (int kk = 0; kk < 4; ++kk) {
        bf16x8 afr[2];
#pragma unroll
        for (int m = 0; m < 2; ++m) {
          const float* src;
          if (kk < 2) src = ent + (m ? h1 : h0) + kk * 32 + g4 * 8;
          else        src = rel + (m ? rr1 : rr0) + (kk - 2) * 32 + g4 * 8;
          f32x4 lo = *(const f32x4*)(src);
          f32x4 hi = *(const f32x4*)(src + 4);
          bf16x8 a;
          a[0] = (__bf16)lo[0]; a[1] = (__bf16)lo[1]; a[2] = (__bf16)lo[2]; a[3] = (__bf16)lo[3];
          a[4] = (__bf16)hi[0]; a[5] = (__bf16)hi[1]; a[6] = (__bf16)hi[2]; a[7] = (__bf16)hi[3];
          afr[m] = a;
        }
#pragma unroll
        for (int n = 0; n < 4; ++n) {
          bf16x8 bS = *(const bf16x8*)(W1t + (n * 16 + r16) * 128 + kk * 32 + g4 * 8);
          bf16x8 bG = *(const bf16x8*)(G1t + (n * 16 + r16) * 128 + kk * 32 + g4 * 8);
#pragma unroll
          for (int m = 0; m < 2; ++m) {
            accS[m][n] = mfma16(afr[m], bS, accS[m][n]);
            accG[m][n] = mfma16(afr[m], bG, accG[m][n]);
          }
        }
      }

      // ReLU + bf16 -> LDS (wave-private rows)
#pragma unroll
      for (int m = 0; m < 2; ++m)
#pragma unroll
        for (int n = 0; n < 4; ++n)
#pragma unroll
          for (int i = 0; i < 4; ++i) {
            const int row = rb + m * 16 + g4 * 4 + i;
            const int col = n * 16 + r16;
            s1buf[row][col] = (__bf16)fmaxf(accS[m][n][i], 0.f);
            g1buf[row][col] = (__bf16)fmaxf(accG[m][n][i], 0.f);
          }

      // ---- GEMM2: s1@W2, g1@G2 (K=64) ----
      f32x4 acc2S[2][4], acc2G[2][4];
#pragma unroll
      for (int m = 0; m < 2; ++m)
#pragma unroll
        for (int n = 0; n < 4; ++n) { acc2S[m][n] = zero4; acc2G[m][n] = zero4; }
#pragma unroll
      for (int kk = 0; kk < 2; ++kk) {
        bf16x8 aS[2], aG[2];
#pragma unroll
        for (int m = 0; m < 2; ++m) {
          const int tok = rb + m * 16 + r16;
          aS[m] = *(const bf16x8*)&s1buf[tok][kk * 32 + g4 * 8];
          aG[m] = *(const bf16x8*)&g1buf[tok][kk * 32 + g4 * 8];
        }
#pragma unroll
        for (int n = 0; n < 4; ++n) {
          bf16x8 bS = *(const bf16x8*)(W2t + (n * 16 + r16) * 64 + kk * 32 + g4 * 8);
          bf16x8 bG = *(const bf16x8*)(G2t + (n * 16 + r16) * 64 + kk * 32 + g4 * 8);
#pragma unroll
          for (int m = 0; m < 2; ++m) {
            acc2S[m][n] = mfma16(aS[m], bS, acc2S[m][n]);
            acc2G[m][n] = mfma16(aG[m], bG, acc2G[m][n]);
          }
        }
      }

      // s2 = relu(...) -> reuse s1buf (this wave already consumed its s1 rows)
#pragma unroll
      for (int m = 0; m < 2; ++m)
#pragma unroll
        for (int n = 0; n < 4; ++n)
#pragma unroll
          for (int i = 0; i < 4; ++i)
            s1buf[rb + m * 16 + g4 * 4 + i][n * 16 + r16] = (__bf16)fmaxf(acc2S[m][n][i], 0.f);

      // s3 = sigmoid(s2 @ w3); softmax over the 32 neighbors (lanes 0..31)
      float sc = 0.f;
      if (lane < 32) {
        float dot = 0.f;
        const __bf16* srow = &s1buf[rb + lane][0];
#pragma unroll
        for (int c = 0; c < 64; ++c) dot += (float)srow[c] * w3[c];
        sc = 1.f / (1.f + __expf(-dot));
      }
      float mx = sc;
#pragma unroll
      for (int off = 16; off >= 1; off >>= 1) mx = fmaxf(mx, __shfl_xor(mx, off));
      float ex = __expf(sc - mx);
      float sm = ex;
#pragma unroll
      for (int off = 16; off >= 1; off >>= 1) sm += __shfl_xor(sm, off);
      if (lane < 32) attbuf[rb + lane] = ex / sm;

      // epilogue: out[d] = sum_t att[t] * 2*sigmoid(g2[t,d]) * t_e[t,d]
      float outn[4] = {0.f, 0.f, 0.f, 0.f};
#pragma unroll
      for (int m = 0; m < 2; ++m)
#pragma unroll
        for (int i = 0; i < 4; ++i) {
          const int trow = m * 16 + g4 * 4 + i;
          const float at = attbuf[rb + trow];
          const float* te = ent + tidx[rb + trow] * DIM;
#pragma unroll
          for (int n = 0; n < 4; ++n) {
            const float g2 = 2.f / (1.f + __expf(-acc2G[m][n][i]));
            outn[n] += at * g2 * te[n * 16 + r16];
          }
        }
#pragma unroll
      for (int n = 0; n < 4; ++n) {   // reduce over the 4 g4 groups
        outn[n] += __shfl_xor(outn[n], 16);
        outn[n] += __shfl_xor(outn[n], 32);
      }
      if (tower == 0) {
#pragma unroll
        for (int n = 0; n < 4; ++n) uvec[n] = outn[n];
      } else {
#pragma unroll
        for (int n = 0; n < 4; ++n) layer_dot += uvec[n] * outn[n];
      }
    } // tower
  } // l

  // ---- origins + final score (lane = d) ----
  float uo = 0.f;
  const int ib0 = b * NTOK;            // user_h layer 0
#pragma unroll 8
  for (int t = 0; t < NTOK; ++t) uo += ent[user_h[ib0 + t] * DIM + lane];
  uo *= (1.f / 32.f);
  const float io = ent[items[b] * DIM + lane];
  // each layer-col is replicated 4x across lanes -> scale layer_dot by 1/4
  float part = uo * io + 0.25f * layer_dot;
#pragma unroll
  for (int off = 32; off >= 1; off >>= 1) part += __shfl_xor(part, off);
  if (lane == 0) out[b] = 1.f / (1.f + __expf(-part));
}

extern "C" void kernel_launch(void* const* d_in, const int* in_sizes, int n_in,
                              void* d_out, int out_size, void* d_ws, size_t ws_size,
                              hipStream_t stream) {
  const int*   items  = (const int*)d_in[1];
  const int*   user_h = (const int*)d_in[2];
  const int*   user_r = (const int*)d_in[3];
  const int*   user_t = (const int*)d_in[4];
  const int*   item_h = (const int*)d_in[5];
  const int*   item_r = (const int*)d_in[6];
  const int*   item_t = (const int*)d_in[7];
  const float* ent    = (const float*)d_in[8];
  const float* rel    = (const float*)d_in[9];
  const float* W1     = (const float*)d_in[10];
  const float* W2     = (const float*)d_in[11];
  const float* w3     = (const float*)d_in[12];
  const float* G1     = (const float*)d_in[13];
  const float* G2     = (const float*)d_in[14];
  __bf16* wt = (__bf16*)d_ws;          // 49152 B used
  float* out = (float*)d_out;

  prep_w<<<dim3(48), dim3(256), 0, stream>>>(W1, G1, W2, G2, wt);
  ckan_main<<<dim3(NB / 4), dim3(256), 0, stream>>>(
      items, user_h, user_r, user_t, item_h, item_r, item_t,
      ent, rel, wt, w3, out);
}